// Round 1
// baseline (487.497 us; speedup 1.0000x reference)
//
#include <hip/hip_runtime.h>
#include <math.h>

#define TT 2048
#define HH 1024
#define NE 40
#define ER 32
#define II 512
#define TOPK 4
#define RSCALE 2.5f
#define MAXW 64    // max m-tiles of 256: 8192/256 + 32

typedef __bf16 bf16x8 __attribute__((ext_vector_type(8)));
typedef float f32x4 __attribute__((ext_vector_type(4)));

__device__ __forceinline__ bf16x8 cvt_bf8(float4 lo, float4 hi) {
  bf16x8 r;
  r[0] = (__bf16)lo.x; r[1] = (__bf16)lo.y; r[2] = (__bf16)lo.z; r[3] = (__bf16)lo.w;
  r[4] = (__bf16)hi.x; r[5] = (__bf16)hi.y; r[6] = (__bf16)hi.z; r[7] = (__bf16)hi.w;
  return r;
}

// ---------------- K1: fused router: logits(fp32) + softmax + top4 ----------
// One wave per token. fp32 logits REQUIRED (bf16 error ~2.6e-3 flips top-4).
// Also: out = hidden * zero_total, hid_bf = bf16(hidden) — single hidden read.
__global__ __launch_bounds__(256) void k_router(const float* __restrict__ hidden,
                                                const float* __restrict__ rw,
                                                const float* __restrict__ bias,
                                                float* __restrict__ out,
                                                int* __restrict__ tok4_id,
                                                float* __restrict__ tok4_w,
                                                __bf16* __restrict__ hid_bf) {
  int lane = threadIdx.x & 63;
  int t = blockIdx.x * 4 + (threadIdx.x >> 6);
  const float* hrow = hidden + (size_t)t * HH;
  float4 hv[4];
  #pragma unroll
  for (int c = 0; c < 4; c++) hv[c] = *(const float4*)(hrow + c * 256 + lane * 4);

  float mylg = -INFINITY;
  for (int e = 0; e < NE; e++) {
    const float* wrow = rw + (size_t)e * HH;
    float p = 0.f;
    #pragma unroll
    for (int c = 0; c < 4; c++) {
      float4 w4 = *(const float4*)(wrow + c * 256 + lane * 4);
      p += hv[c].x * w4.x + hv[c].y * w4.y + hv[c].z * w4.z + hv[c].w * w4.w;
    }
    #pragma unroll
    for (int off = 32; off; off >>= 1) p += __shfl_xor(p, off);
    if (lane == e) mylg = p;
  }
  float m = mylg;
  #pragma unroll
  for (int off = 32; off; off >>= 1) m = fmaxf(m, __shfl_xor(m, off));
  float p = (lane < NE) ? expf(mylg - m) : 0.f;
  float s = p;
  #pragma unroll
  for (int off = 32; off; off >>= 1) s += __shfl_xor(s, off);
  float score = p / s;
  float v = (lane < NE) ? score + bias[lane] : -INFINITY;
  int ids[TOPK]; float wv[TOPK];
  #pragma unroll
  for (int k = 0; k < TOPK; k++) {
    float mv = v;
    int mi = (lane < NE) ? lane : 63;
    #pragma unroll
    for (int off = 32; off; off >>= 1) {      // argmax, tie -> lower idx
      float ov = __shfl_xor(mv, off);
      int oi = __shfl_xor(mi, off);
      if (ov > mv || (ov == mv && oi < mi)) { mv = ov; mi = oi; }
    }
    ids[k] = mi;
    wv[k] = RSCALE * __shfl(score, mi);       // weight from UNBIASED score
    if (lane == mi) v = -INFINITY;
  }
  float zt = 0.f;
  #pragma unroll
  for (int k = 0; k < TOPK; k++) if (ids[k] >= ER) zt += wv[k];
  if (lane == 0) {
    #pragma unroll
    for (int k = 0; k < TOPK; k++) {
      tok4_id[t * TOPK + k] = ids[k];
      tok4_w[t * TOPK + k] = wv[k];
    }
  }
  #pragma unroll
  for (int c = 0; c < 4; c++) {
    int j = c * 256 + lane * 4;
    float4 h4 = hv[c];
    *(float4*)(out + (size_t)t * HH + j) =
        make_float4(h4.x * zt, h4.y * zt, h4.z * zt, h4.w * zt);
    union { __bf16 h[4]; uint2 u; } pk;
    pk.h[0] = (__bf16)h4.x; pk.h[1] = (__bf16)h4.y;
    pk.h[2] = (__bf16)h4.z; pk.h[3] = (__bf16)h4.w;
    *(uint2*)(hid_bf + (size_t)t * HH + j) = pk.u;
  }
}

// ---------------- K2: single-block count + scan + scatter (LDS counters) ---
__global__ __launch_bounds__(256) void k_scanscatter(const int* __restrict__ tok4_id,
                                                     const float* __restrict__ tok4_w,
                                                     int* __restrict__ cnt,
                                                     int* __restrict__ offs,
                                                     int* __restrict__ wl_e,
                                                     int* __restrict__ wl_m0,
                                                     int* __restrict__ nwork,
                                                     int* __restrict__ pair_tok,
                                                     float* __restrict__ pair_w) {
  __shared__ int scnt[32];
  __shared__ int scur[32];
  int tid = threadIdx.x;
  if (tid < 32) scnt[tid] = 0;
  __syncthreads();
  int ids[32]; float wv[32];
  #pragma unroll
  for (int i = 0; i < 32; i++) {              // 8192 entries, coalesced
    int idx = i * 256 + tid;
    ids[i] = tok4_id[idx];
    wv[i] = tok4_w[idx];
    if (ids[i] < ER) atomicAdd(&scnt[ids[i]], 1);
  }
  __syncthreads();
  if (tid < 64) {                             // one wave does the scan
    int lane = tid;
    int c = (lane < ER) ? scnt[lane] : 0;
    int ts = (c + 255) >> 8;                  // 256-row tiles
    int ps = c, pt = ts;
    #pragma unroll
    for (int off = 1; off < 32; off <<= 1) {
      int v1 = __shfl_up(ps, off);
      int v2 = __shfl_up(pt, off);
      if (lane >= off) { ps += v1; pt += v2; }
    }
    if (lane < ER) {
      int o = ps - c;
      offs[lane] = o; cnt[lane] = c; scur[lane] = o;
      int tb = pt - ts;
      for (int i = 0; i < ts; i++) { wl_e[tb + i] = lane; wl_m0[tb + i] = i * 256; }
    }
    if (lane == 31) *nwork = pt;
  }
  __syncthreads();
  #pragma unroll
  for (int i = 0; i < 32; i++) {
    if (ids[i] < ER) {
      int pos = atomicAdd(&scur[ids[i]], 1);  // absolute slot (scur seeded w/ offs)
      pair_tok[pos] = (i * 256 + tid) >> 2;
      pair_w[pos] = wv[i];
    }
  }
}

// ---------------- K3: h = silu(X@Wg^T)*(X@Wu^T), M=256 tile ----------------
// grid: MAXW x 16 (32 gate + 32 up cols each). NO LDS STAGING: the
// 16x16x32 MFMA fragment is a contiguous 16B run of one row for both A and
// B, so fragments load straight from global (A: bf16 gather rows via tl[];
// B: fp32 weight rows, converted in-register). No barriers in the K loop —
// waves drift freely, loads pipeline across iterations (latency-bound fix:
// in-flight bytes were capped ~2.3KB/CU by the old barrier lockstep).
__global__ __launch_bounds__(256) void k_w13(const __bf16* __restrict__ hid_bf,
                                             const float* __restrict__ w13,
                                             const int* __restrict__ cnt,
                                             const int* __restrict__ offs,
                                             const int* __restrict__ pair_tok,
                                             const int* __restrict__ wl_e,
                                             const int* __restrict__ wl_m0,
                                             const int* __restrict__ nwork,
                                             __bf16* __restrict__ h_buf) {
  int bx = blockIdx.x;
  if (bx >= *nwork) return;
  int e = wl_e[bx], m0w = wl_m0[bx];
  int M = cnt[e] - m0w; if (M > 256) M = 256;
  int base = offs[e] + m0w;
  int n0 = blockIdx.y * 32;

  __shared__ int tl[256];
  int tid = threadIdx.x;
  int lane = tid & 63, w = tid >> 6;
  int quad = lane >> 4, rr = lane & 15;

  tl[tid] = pair_tok[base + ((tid < M) ? tid : 0)];
  __syncthreads();

  // Per-lane fragment source pointers (quad selects the 8-elem k-chunk).
  const __bf16* ap[4];
  #pragma unroll
  for (int i = 0; i < 4; i++)
    ap[i] = hid_bf + (size_t)tl[w * 64 + i * 16 + rr] * HH + quad * 8;

  const float* wbase = w13 + (size_t)e * (2 * II) * HH;
  const float* bgp[2];
  const float* bup[2];
  #pragma unroll
  for (int j = 0; j < 2; j++) {
    bgp[j] = wbase + (size_t)(n0 + j * 16 + rr) * HH + quad * 8;
    bup[j] = wbase + (size_t)(II + n0 + j * 16 + rr) * HH + quad * 8;
  }

  f32x4 accg[4][2] = {};
  f32x4 accu[4][2] = {};

  #pragma unroll 2
  for (int k0 = 0; k0 < HH; k0 += 32) {
    bf16x8 a[4];
    #pragma unroll
    for (int i = 0; i < 4; i++) a[i] = *(const bf16x8*)(ap[i] + k0);
    bf16x8 bg[2], bu[2];
    #pragma unroll
    for (int j = 0; j < 2; j++) {
      float4 lo = *(const float4*)(bgp[j] + k0);
      float4 hi = *(const float4*)(bgp[j] + k0 + 4);
      bg[j] = cvt_bf8(lo, hi);
    }
    #pragma unroll
    for (int j = 0; j < 2; j++) {
      float4 lo = *(const float4*)(bup[j] + k0);
      float4 hi = *(const float4*)(bup[j] + k0 + 4);
      bu[j] = cvt_bf8(lo, hi);
    }
    #pragma unroll
    for (int i = 0; i < 4; i++)
      #pragma unroll
      for (int j = 0; j < 2; j++) {
        accg[i][j] = __builtin_amdgcn_mfma_f32_16x16x32_bf16(a[i], bg[j], accg[i][j], 0, 0, 0);
        accu[i][j] = __builtin_amdgcn_mfma_f32_16x16x32_bf16(a[i], bu[j], accu[i][j], 0, 0, 0);
      }
  }
  #pragma unroll
  for (int i = 0; i < 4; i++)
    #pragma unroll
    for (int j = 0; j < 2; j++)
      #pragma unroll
      for (int l = 0; l < 4; l++) {
        int m = w * 64 + i * 16 + quad * 4 + l;
        if (m < M) {
          float g = accg[i][j][l], u = accu[i][j][l];
          float hv = g / (1.f + expf(-g)) * u;
          h_buf[(size_t)(base + m) * II + n0 + j * 16 + rr] = (__bf16)hv;
        }
      }
}

// ---------------- K4: out[t] += w_p * (h @ w2[e]^T), M=256 tile ------------
// grid: MAXW x 16 (64 H-cols each). Same direct-load structure as k_w13;
// A rows (h_buf) are contiguous, no gather needed in the K loop.
__global__ __launch_bounds__(256) void k_w2(const __bf16* __restrict__ h_buf,
                                            const float* __restrict__ w2,
                                            const int* __restrict__ cnt,
                                            const int* __restrict__ offs,
                                            const int* __restrict__ pair_tok,
                                            const float* __restrict__ pair_w,
                                            const int* __restrict__ wl_e,
                                            const int* __restrict__ wl_m0,
                                            const int* __restrict__ nwork,
                                            float* __restrict__ out) {
  int bx = blockIdx.x;
  if (bx >= *nwork) return;
  int e = wl_e[bx], m0w = wl_m0[bx];
  int M = cnt[e] - m0w; if (M > 256) M = 256;
  int base = offs[e] + m0w;
  int h0 = blockIdx.y * 64;

  __shared__ int tl[256];
  __shared__ float wl[256];

  int tid = threadIdx.x;
  int lane = tid & 63, w = tid >> 6;
  int quad = lane >> 4, rr = lane & 15;

  {
    int ok = tid < M;
    tl[tid] = ok ? pair_tok[base + tid] : 0;
    wl[tid] = ok ? pair_w[base + tid] : 0.f;
  }
  __syncthreads();

  // rows >= M read h_buf overrun region: garbage but masked at the write
  const __bf16* ap[4];
  #pragma unroll
  for (int i = 0; i < 4; i++)
    ap[i] = h_buf + (size_t)(base + w * 64 + i * 16 + rr) * II + quad * 8;

  const float* w_base = w2 + (size_t)e * HH * II;
  const float* bp[4];
  #pragma unroll
  for (int j = 0; j < 4; j++)
    bp[j] = w_base + (size_t)(h0 + j * 16 + rr) * II + quad * 8;

  f32x4 acc[4][4] = {};

  #pragma unroll 2
  for (int k0 = 0; k0 < II; k0 += 32) {
    bf16x8 a[4];
    #pragma unroll
    for (int i = 0; i < 4; i++) a[i] = *(const bf16x8*)(ap[i] + k0);
    bf16x8 b[4];
    #pragma unroll
    for (int j = 0; j < 4; j++) {
      float4 lo = *(const float4*)(bp[j] + k0);
      float4 hi = *(const float4*)(bp[j] + k0 + 4);
      b[j] = cvt_bf8(lo, hi);
    }
    #pragma unroll
    for (int i = 0; i < 4; i++)
      #pragma unroll
      for (int j = 0; j < 4; j++)
        acc[i][j] = __builtin_amdgcn_mfma_f32_16x16x32_bf16(a[i], b[j], acc[i][j], 0, 0, 0);
  }
  #pragma unroll
  for (int i = 0; i < 4; i++)
    #pragma unroll
    for (int l = 0; l < 4; l++) {
      int m = w * 64 + i * 16 + quad * 4 + l;
      if (m < M) {
        int t = tl[m];
        float wp = wl[m];
        #pragma unroll
        for (int j = 0; j < 4; j++)
          atomicAdd(&out[(size_t)t * HH + h0 + j * 16 + rr], acc[i][j][l] * wp);
      }
    }
}

extern "C" void kernel_launch(void* const* d_in, const int* in_sizes, int n_in,
                              void* d_out, int out_size, void* d_ws, size_t ws_size,
                              hipStream_t stream) {
  const float* hidden = (const float*)d_in[0];
  const float* rw     = (const float*)d_in[1];
  const float* bias   = (const float*)d_in[2];
  const float* w13    = (const float*)d_in[3];
  const float* w2     = (const float*)d_in[4];
  float* out = (float*)d_out;

  int* ws_i = (int*)d_ws;
  int* tok4_id = ws_i;                                    // TT*4
  float* tok4_w = (float*)(tok4_id + TT * TOPK);          // TT*4
  int* pair_tok = (int*)(tok4_w + TT * TOPK);             // TT*4
  float* pair_w = (float*)(pair_tok + TT * TOPK);         // TT*4
  int* cnt = (int*)(pair_w + TT * TOPK);                  // 32
  int* offs = cnt + 32;                                   // 32
  int* wl_e = offs + 32;                                  // 64
  int* wl_m0 = wl_e + 64;                                 // 64
  int* nwork = wl_m0 + 64;                                // + pad to 16B align
  __bf16* hid_bf = (__bf16*)(nwork + 64);                 // TT*HH
  __bf16* h_buf = hid_bf + (size_t)TT * HH;               // (TT*4+256)*II

  k_router<<<dim3(TT / 4), dim3(256), 0, stream>>>(hidden, rw, bias, out,
                                                   tok4_id, tok4_w, hid_bf);
  k_scanscatter<<<dim3(1), dim3(256), 0, stream>>>(tok4_id, tok4_w, cnt, offs,
                                                   wl_e, wl_m0, nwork, pair_tok, pair_w);
  k_w13<<<dim3(MAXW, 16), dim3(256), 0, stream>>>(hid_bf, w13, cnt, offs, pair_tok,
                                                  wl_e, wl_m0, nwork, h_buf);
  k_w2<<<dim3(MAXW, 16), dim3(256), 0, stream>>>(h_buf, w2, cnt, offs, pair_tok, pair_w,
                                                 wl_e, wl_m0, nwork, out);
}

// Round 2
// 374.894 us; speedup vs baseline: 1.3004x; 1.3004x over previous
//
#include <hip/hip_runtime.h>
#include <math.h>

#define TT 2048
#define HH 1024
#define NE 40
#define ER 32
#define II 512
#define TOPK 4
#define RSCALE 2.5f
#define MAXW 64    // max m-tiles of 256: 8192/256 + 32

typedef __bf16 bf16x8 __attribute__((ext_vector_type(8)));
typedef float f32x4 __attribute__((ext_vector_type(4)));

__device__ __forceinline__ bf16x8 cvt_bf8(float4 lo, float4 hi) {
  bf16x8 r;
  r[0] = (__bf16)lo.x; r[1] = (__bf16)lo.y; r[2] = (__bf16)lo.z; r[3] = (__bf16)lo.w;
  r[4] = (__bf16)hi.x; r[5] = (__bf16)hi.y; r[6] = (__bf16)hi.z; r[7] = (__bf16)hi.w;
  return r;
}

// ---------------- K1: fused router: logits(fp32) + softmax + top4 ----------
// One wave per token. fp32 logits REQUIRED (bf16 error ~2.6e-3 flips top-4).
// Also: out = hidden * zero_total, hid_bf = bf16(hidden) — single hidden read.
__global__ __launch_bounds__(256) void k_router(const float* __restrict__ hidden,
                                                const float* __restrict__ rw,
                                                const float* __restrict__ bias,
                                                float* __restrict__ out,
                                                int* __restrict__ tok4_id,
                                                float* __restrict__ tok4_w,
                                                __bf16* __restrict__ hid_bf) {
  int lane = threadIdx.x & 63;
  int t = blockIdx.x * 4 + (threadIdx.x >> 6);
  const float* hrow = hidden + (size_t)t * HH;
  float4 hv[4];
  #pragma unroll
  for (int c = 0; c < 4; c++) hv[c] = *(const float4*)(hrow + c * 256 + lane * 4);

  float mylg = -INFINITY;
  for (int e = 0; e < NE; e++) {
    const float* wrow = rw + (size_t)e * HH;
    float p = 0.f;
    #pragma unroll
    for (int c = 0; c < 4; c++) {
      float4 w4 = *(const float4*)(wrow + c * 256 + lane * 4);
      p += hv[c].x * w4.x + hv[c].y * w4.y + hv[c].z * w4.z + hv[c].w * w4.w;
    }
    #pragma unroll
    for (int off = 32; off; off >>= 1) p += __shfl_xor(p, off);
    if (lane == e) mylg = p;
  }
  float m = mylg;
  #pragma unroll
  for (int off = 32; off; off >>= 1) m = fmaxf(m, __shfl_xor(m, off));
  float p = (lane < NE) ? expf(mylg - m) : 0.f;
  float s = p;
  #pragma unroll
  for (int off = 32; off; off >>= 1) s += __shfl_xor(s, off);
  float score = p / s;
  float v = (lane < NE) ? score + bias[lane] : -INFINITY;
  int ids[TOPK]; float wv[TOPK];
  #pragma unroll
  for (int k = 0; k < TOPK; k++) {
    float mv = v;
    int mi = (lane < NE) ? lane : 63;
    #pragma unroll
    for (int off = 32; off; off >>= 1) {      // argmax, tie -> lower idx
      float ov = __shfl_xor(mv, off);
      int oi = __shfl_xor(mi, off);
      if (ov > mv || (ov == mv && oi < mi)) { mv = ov; mi = oi; }
    }
    ids[k] = mi;
    wv[k] = RSCALE * __shfl(score, mi);       // weight from UNBIASED score
    if (lane == mi) v = -INFINITY;
  }
  float zt = 0.f;
  #pragma unroll
  for (int k = 0; k < TOPK; k++) if (ids[k] >= ER) zt += wv[k];
  if (lane == 0) {
    #pragma unroll
    for (int k = 0; k < TOPK; k++) {
      tok4_id[t * TOPK + k] = ids[k];
      tok4_w[t * TOPK + k] = wv[k];
    }
  }
  #pragma unroll
  for (int c = 0; c < 4; c++) {
    int j = c * 256 + lane * 4;
    float4 h4 = hv[c];
    *(float4*)(out + (size_t)t * HH + j) =
        make_float4(h4.x * zt, h4.y * zt, h4.z * zt, h4.w * zt);
    union { __bf16 h[4]; uint2 u; } pk;
    pk.h[0] = (__bf16)h4.x; pk.h[1] = (__bf16)h4.y;
    pk.h[2] = (__bf16)h4.z; pk.h[3] = (__bf16)h4.w;
    *(uint2*)(hid_bf + (size_t)t * HH + j) = pk.u;
  }
}

// ---------------- K2: single-block count + scan + scatter (LDS counters) ---
__global__ __launch_bounds__(256) void k_scanscatter(const int* __restrict__ tok4_id,
                                                     const float* __restrict__ tok4_w,
                                                     int* __restrict__ cnt,
                                                     int* __restrict__ offs,
                                                     int* __restrict__ wl_e,
                                                     int* __restrict__ wl_m0,
                                                     int* __restrict__ nwork,
                                                     int* __restrict__ pair_tok,
                                                     float* __restrict__ pair_w) {
  __shared__ int scnt[32];
  __shared__ int scur[32];
  int tid = threadIdx.x;
  if (tid < 32) scnt[tid] = 0;
  __syncthreads();
  int ids[32]; float wv[32];
  #pragma unroll
  for (int i = 0; i < 32; i++) {              // 8192 entries, coalesced
    int idx = i * 256 + tid;
    ids[i] = tok4_id[idx];
    wv[i] = tok4_w[idx];
    if (ids[i] < ER) atomicAdd(&scnt[ids[i]], 1);
  }
  __syncthreads();
  if (tid < 64) {                             // one wave does the scan
    int lane = tid;
    int c = (lane < ER) ? scnt[lane] : 0;
    int ts = (c + 255) >> 8;                  // 256-row tiles
    int ps = c, pt = ts;
    #pragma unroll
    for (int off = 1; off < 32; off <<= 1) {
      int v1 = __shfl_up(ps, off);
      int v2 = __shfl_up(pt, off);
      if (lane >= off) { ps += v1; pt += v2; }
    }
    if (lane < ER) {
      int o = ps - c;
      offs[lane] = o; cnt[lane] = c; scur[lane] = o;
      int tb = pt - ts;
      for (int i = 0; i < ts; i++) { wl_e[tb + i] = lane; wl_m0[tb + i] = i * 256; }
    }
    if (lane == 31) *nwork = pt;
  }
  __syncthreads();
  #pragma unroll
  for (int i = 0; i < 32; i++) {
    if (ids[i] < ER) {
      int pos = atomicAdd(&scur[ids[i]], 1);  // absolute slot (scur seeded w/ offs)
      pair_tok[pos] = (i * 256 + tid) >> 2;
      pair_w[pos] = wv[i];
    }
  }
}

// ---------------- K3: h = silu(X@Wg^T)*(X@Wu^T), M=256 tile ----------------
// Round-1 lesson: direct-from-global fragment loads are 16 scattered rows
// per VMEM op — must stage via LDS to keep global loads coalesced. Fix the
// real (latency) bottleneck instead with a 2-phase double-buffered pipeline:
//   issue t+1 global loads -> regs | ds_read+MFMA on buf[cur] |
//   ds_write regs -> buf[cur^1] | ONE barrier | swap.
// LDS is unpadded [*][64] with XOR chunk-swizzle (byte ^= (row&7)<<4) so
// both ds_write_b128 and ds_read_b128 are conflict-free; 80KB total ->
// 2 blocks/CU, ~80KB in flight/CU.
__global__ __launch_bounds__(256) void k_w13(const __bf16* __restrict__ hid_bf,
                                             const float* __restrict__ w13,
                                             const int* __restrict__ cnt,
                                             const int* __restrict__ offs,
                                             const int* __restrict__ pair_tok,
                                             const int* __restrict__ wl_e,
                                             const int* __restrict__ wl_m0,
                                             const int* __restrict__ nwork,
                                             __bf16* __restrict__ h_buf) {
  int bx = blockIdx.x;
  if (bx >= *nwork) return;
  int e = wl_e[bx], m0w = wl_m0[bx];
  int M = cnt[e] - m0w; if (M > 256) M = 256;
  int base = offs[e] + m0w;
  int n0 = blockIdx.y * 32;

  __shared__ __bf16 As[2][256][64];   // 64KB, swizzled chunks
  __shared__ __bf16 Bs[2][64][64];    // 16KB: rows 0-31 gate, 32-63 up

  int tid = threadIdx.x;
  int lane = tid & 63, w = tid >> 6;
  int quad = lane >> 4, rr = lane & 15;
  int ga = tid & 7;                   // global chunk this thread stages
  int sr = tid >> 3;                  // staging row-within-32

  // A staging sources: slot s = p*256+tid -> row = p*32+sr, chunk ga (8 bf16)
  const __bf16* asrc[8];
  int awoff[8];
  #pragma unroll
  for (int p = 0; p < 8; p++) {
    int row = p * 32 + sr;
    int tok = pair_tok[base + ((row < M) ? row : 0)];
    asrc[p] = hid_bf + (size_t)tok * HH + ga * 8;
    awoff[p] = row * 128 + ((ga ^ (row & 7)) << 4);
  }
  // B staging sources: 64 rows x 8 chunks = 2 issues
  const float* wbase = w13 + (size_t)e * (2 * II) * HH;
  const float* bsrc[2];
  int bwoff[2];
  #pragma unroll
  for (int p = 0; p < 2; p++) {
    int row = p * 32 + sr;
    int wrow = (row < 32) ? (n0 + row) : (II + n0 + row - 32);
    bsrc[p] = wbase + (size_t)wrow * HH + ga * 8;
    bwoff[p] = row * 128 + ((ga ^ (row & 7)) << 4);
  }

  // prologue: stage tile 0
  uint4 areg[8]; bf16x8 breg[2];
  #pragma unroll
  for (int p = 0; p < 8; p++) areg[p] = *(const uint4*)(asrc[p]);
  #pragma unroll
  for (int p = 0; p < 2; p++) {
    float4 lo = *(const float4*)(bsrc[p]);
    float4 hi = *(const float4*)(bsrc[p] + 4);
    breg[p] = cvt_bf8(lo, hi);
  }
  {
    char* a0 = (char*)&As[0][0][0];
    char* b0 = (char*)&Bs[0][0][0];
    #pragma unroll
    for (int p = 0; p < 8; p++) *(uint4*)(a0 + awoff[p]) = areg[p];
    #pragma unroll
    for (int p = 0; p < 2; p++) *(bf16x8*)(b0 + bwoff[p]) = breg[p];
  }
  __syncthreads();

  f32x4 accg[4][2] = {};
  f32x4 accu[4][2] = {};
  int cur = 0;
  int rx = rr & 7;

  for (int t = 0; t < HH / 64; t++) {
    bool pf = (t + 1 < HH / 64);
    int k0n = (t + 1) * 64;
    if (pf) {                               // issue t+1 loads (overlap MFMA)
      #pragma unroll
      for (int p = 0; p < 8; p++) areg[p] = *(const uint4*)(asrc[p] + k0n);
      #pragma unroll
      for (int p = 0; p < 2; p++) {
        float4 lo = *(const float4*)(bsrc[p] + k0n);
        float4 hi = *(const float4*)(bsrc[p] + k0n + 4);
        breg[p] = cvt_bf8(lo, hi);
      }
    }
    const char* ac = (const char*)&As[cur][0][0];
    const char* bc = (const char*)&Bs[cur][0][0];
    #pragma unroll
    for (int ks = 0; ks < 2; ks++) {
      int cx = ((ks * 4 + quad) ^ rx) << 4;
      bf16x8 a[4], bg[2], bu[2];
      #pragma unroll
      for (int i = 0; i < 4; i++)
        a[i] = *(const bf16x8*)(ac + (w * 64 + i * 16 + rr) * 128 + cx);
      #pragma unroll
      for (int j = 0; j < 2; j++) {
        bg[j] = *(const bf16x8*)(bc + (j * 16 + rr) * 128 + cx);
        bu[j] = *(const bf16x8*)(bc + (32 + j * 16 + rr) * 128 + cx);
      }
      #pragma unroll
      for (int i = 0; i < 4; i++)
        #pragma unroll
        for (int j = 0; j < 2; j++) {
          accg[i][j] = __builtin_amdgcn_mfma_f32_16x16x32_bf16(a[i], bg[j], accg[i][j], 0, 0, 0);
          accu[i][j] = __builtin_amdgcn_mfma_f32_16x16x32_bf16(a[i], bu[j], accu[i][j], 0, 0, 0);
        }
    }
    if (pf) {                               // write-late into the other buffer
      char* an = (char*)&As[cur ^ 1][0][0];
      char* bn = (char*)&Bs[cur ^ 1][0][0];
      #pragma unroll
      for (int p = 0; p < 8; p++) *(uint4*)(an + awoff[p]) = areg[p];
      #pragma unroll
      for (int p = 0; p < 2; p++) *(bf16x8*)(bn + bwoff[p]) = breg[p];
    }
    __syncthreads();
    cur ^= 1;
  }

  #pragma unroll
  for (int i = 0; i < 4; i++)
    #pragma unroll
    for (int j = 0; j < 2; j++)
      #pragma unroll
      for (int l = 0; l < 4; l++) {
        int m = w * 64 + i * 16 + quad * 4 + l;
        if (m < M) {
          float g = accg[i][j][l], u = accu[i][j][l];
          float hv = g / (1.f + expf(-g)) * u;
          h_buf[(size_t)(base + m) * II + n0 + j * 16 + rr] = (__bf16)hv;
        }
      }
}

// ---------------- K4: out[t] += w_p * (h @ w2[e]^T), M=256 tile ------------
// Same 2-phase double-buffered pipeline as k_w13. A rows contiguous.
__global__ __launch_bounds__(256) void k_w2(const __bf16* __restrict__ h_buf,
                                            const float* __restrict__ w2,
                                            const int* __restrict__ cnt,
                                            const int* __restrict__ offs,
                                            const int* __restrict__ pair_tok,
                                            const float* __restrict__ pair_w,
                                            const int* __restrict__ wl_e,
                                            const int* __restrict__ wl_m0,
                                            const int* __restrict__ nwork,
                                            float* __restrict__ out) {
  int bx = blockIdx.x;
  if (bx >= *nwork) return;
  int e = wl_e[bx], m0w = wl_m0[bx];
  int M = cnt[e] - m0w; if (M > 256) M = 256;
  int base = offs[e] + m0w;
  int h0 = blockIdx.y * 64;

  __shared__ __bf16 As[2][256][64];   // 64KB
  __shared__ __bf16 Bs[2][64][64];    // 16KB
  __shared__ int tl[256];
  __shared__ float wl[256];

  int tid = threadIdx.x;
  int lane = tid & 63, w = tid >> 6;
  int quad = lane >> 4, rr = lane & 15;
  int ga = tid & 7;
  int sr = tid >> 3;

  {
    int ok = tid < M;
    tl[tid] = ok ? pair_tok[base + tid] : 0;
    wl[tid] = ok ? pair_w[base + tid] : 0.f;
  }

  // A: contiguous h_buf rows (rows >= M read in-bounds junk, masked at write)
  const __bf16* asrc[8];
  int awoff[8];
  #pragma unroll
  for (int p = 0; p < 8; p++) {
    int row = p * 32 + sr;
    asrc[p] = h_buf + (size_t)(base + row) * II + ga * 8;
    awoff[p] = row * 128 + ((ga ^ (row & 7)) << 4);
  }
  // B: w2 rows h0..h0+63
  const float* w_base = w2 + (size_t)e * HH * II;
  const float* bsrc[2];
  int bwoff[2];
  #pragma unroll
  for (int p = 0; p < 2; p++) {
    int row = p * 32 + sr;
    bsrc[p] = w_base + (size_t)(h0 + row) * II + ga * 8;
    bwoff[p] = row * 128 + ((ga ^ (row & 7)) << 4);
  }

  uint4 areg[8]; bf16x8 breg[2];
  #pragma unroll
  for (int p = 0; p < 8; p++) areg[p] = *(const uint4*)(asrc[p]);
  #pragma unroll
  for (int p = 0; p < 2; p++) {
    float4 lo = *(const float4*)(bsrc[p]);
    float4 hi = *(const float4*)(bsrc[p] + 4);
    breg[p] = cvt_bf8(lo, hi);
  }
  {
    char* a0 = (char*)&As[0][0][0];
    char* b0 = (char*)&Bs[0][0][0];
    #pragma unroll
    for (int p = 0; p < 8; p++) *(uint4*)(a0 + awoff[p]) = areg[p];
    #pragma unroll
    for (int p = 0; p < 2; p++) *(bf16x8*)(b0 + bwoff[p]) = breg[p];
  }
  __syncthreads();

  f32x4 acc[4][4] = {};
  int cur = 0;
  int rx = rr & 7;

  for (int t = 0; t < II / 64; t++) {
    bool pf = (t + 1 < II / 64);
    int k0n = (t + 1) * 64;
    if (pf) {
      #pragma unroll
      for (int p = 0; p < 8; p++) areg[p] = *(const uint4*)(asrc[p] + k0n);
      #pragma unroll
      for (int p = 0; p < 2; p++) {
        float4 lo = *(const float4*)(bsrc[p] + k0n);
        float4 hi = *(const float4*)(bsrc[p] + k0n + 4);
        breg[p] = cvt_bf8(lo, hi);
      }
    }
    const char* ac = (const char*)&As[cur][0][0];
    const char* bc = (const char*)&Bs[cur][0][0];
    #pragma unroll
    for (int ks = 0; ks < 2; ks++) {
      int cx = ((ks * 4 + quad) ^ rx) << 4;
      bf16x8 a[4], b[4];
      #pragma unroll
      for (int i = 0; i < 4; i++)
        a[i] = *(const bf16x8*)(ac + (w * 64 + i * 16 + rr) * 128 + cx);
      #pragma unroll
      for (int j = 0; j < 4; j++)
        b[j] = *(const bf16x8*)(bc + (j * 16 + rr) * 128 + cx);
      #pragma unroll
      for (int i = 0; i < 4; i++)
        #pragma unroll
        for (int j = 0; j < 4; j++)
          acc[i][j] = __builtin_amdgcn_mfma_f32_16x16x32_bf16(a[i], b[j], acc[i][j], 0, 0, 0);
    }
    if (pf) {
      char* an = (char*)&As[cur ^ 1][0][0];
      char* bn = (char*)&Bs[cur ^ 1][0][0];
      #pragma unroll
      for (int p = 0; p < 8; p++) *(uint4*)(an + awoff[p]) = areg[p];
      #pragma unroll
      for (int p = 0; p < 2; p++) *(bf16x8*)(bn + bwoff[p]) = breg[p];
    }
    __syncthreads();
    cur ^= 1;
  }

  #pragma unroll
  for (int i = 0; i < 4; i++)
    #pragma unroll
    for (int l = 0; l < 4; l++) {
      int m = w * 64 + i * 16 + quad * 4 + l;
      if (m < M) {
        int t = tl[m];
        float wp = wl[m];
        #pragma unroll
        for (int j = 0; j < 4; j++)
          atomicAdd(&out[(size_t)t * HH + h0 + j * 16 + rr], acc[i][j][l] * wp);
      }
    }
}

extern "C" void kernel_launch(void* const* d_in, const int* in_sizes, int n_in,
                              void* d_out, int out_size, void* d_ws, size_t ws_size,
                              hipStream_t stream) {
  const float* hidden = (const float*)d_in[0];
  const float* rw     = (const float*)d_in[1];
  const float* bias   = (const float*)d_in[2];
  const float* w13    = (const float*)d_in[3];
  const float* w2     = (const float*)d_in[4];
  float* out = (float*)d_out;

  int* ws_i = (int*)d_ws;
  int* tok4_id = ws_i;                                    // TT*4
  float* tok4_w = (float*)(tok4_id + TT * TOPK);          // TT*4
  int* pair_tok = (int*)(tok4_w + TT * TOPK);             // TT*4
  float* pair_w = (float*)(pair_tok + TT * TOPK);         // TT*4
  int* cnt = (int*)(pair_w + TT * TOPK);                  // 32
  int* offs = cnt + 32;                                   // 32
  int* wl_e = offs + 32;                                  // 64
  int* wl_m0 = wl_e + 64;                                 // 64
  int* nwork = wl_m0 + 64;                                // + pad to 16B align
  __bf16* hid_bf = (__bf16*)(nwork + 64);                 // TT*HH
  __bf16* h_buf = hid_bf + (size_t)TT * HH;               // (TT*4+256)*II

  k_router<<<dim3(TT / 4), dim3(256), 0, stream>>>(hidden, rw, bias, out,
                                                   tok4_id, tok4_w, hid_bf);
  k_scanscatter<<<dim3(1), dim3(256), 0, stream>>>(tok4_id, tok4_w, cnt, offs,
                                                   wl_e, wl_m0, nwork, pair_tok, pair_w);
  k_w13<<<dim3(MAXW, 16), dim3(256), 0, stream>>>(hid_bf, w13, cnt, offs, pair_tok,
                                                  wl_e, wl_m0, nwork, h_buf);
  k_w2<<<dim3(MAXW, 16), dim3(256), 0, stream>>>(h_buf, w2, cnt, offs, pair_tok, pair_w,
                                                 wl_e, wl_m0, nwork, out);
}